// Round 1
// 353.335 us; speedup vs baseline: 1.0508x; 1.0508x over previous
//
#include <hip/hip_runtime.h>

#define HW 409600
#define NCH 12

// workspace layout (bytes)
#define OFF_TACC   0                     // 16*3 floats
#define OFF_KACC   256                   // 80*3 floats (960B)
#define OFF_TFAST  1280                  // 16*3 floats (fast-path text sums)
#define OFF_TFB    1536                  // 16*3 floats (fallback text sums)
#define OFF_POSF   1792                  // 16 f32 (pos counts, exact ints)
#define OFF_NEGF   1856                  // 16 f32 (neg counts)
#define OFF_DONE   1920                  // 16 u32
#define OFF_NEGNUM 1984
#define OFF_SEL1   2048
#define OFF_KREM1  2112
#define OFF_SEL2   2176
#define OFF_KREM2  2240
#define OFF_THR    2304                  // 16 f32
#define OFF_HA     4096                  // 16*2048 u32 = 128 KiB
#define OFF_HB     (OFF_HA + 16*2048*4)
#define OFF_HC     (OFF_HB + 16*2048*4)  // 16*1024 u32 = 64 KiB
#define OFF_META_END (OFF_HC + 16*1024*4)
#define OFF_MASK   ((OFF_META_END + 255) & ~255)

__device__ __forceinline__ unsigned flipkey(float x){
  unsigned b = __float_as_uint(x);
  return (b & 0x80000000u) ? ~b : (b | 0x80000000u);   // monotone float->uint
}
__device__ __forceinline__ float unflip(unsigned u){
  unsigned b = (u & 0x80000000u) ? (u ^ 0x80000000u) : ~u;
  return __uint_as_float(b);
}

__device__ __forceinline__ float sigm(float x){
  return __fdividef(1.0f, 1.0f + __expf(-x));
}

// K1 (fused): single pass over ALL data. Per image computes:
//   - pos/neg counts (OHEM decision inputs)
//   - mask bytes (bit0=selk, bit1=tm>0.5, bit2=neg) for the dormant radix path
//   - kernel-dice sums for j=0..4 (mask = selk, OHEM-independent)
//   - text-dice sums for BOTH candidate masks:
//       fast:     m = (tm>0.5)   [negnum==negtotal => thr=min(neg) => sel==tm>0.5]
//       fallback: m = tm (continuous)
__global__ __launch_bounds__(256) void k_main(
    const float* __restrict__ outputs, const float* __restrict__ labels,
    const float* __restrict__ tmask, unsigned char* __restrict__ maskb,
    float* __restrict__ posF, float* __restrict__ negF,
    float* __restrict__ tfastA, float* __restrict__ tfbA,
    float* __restrict__ kaccA)
{
  int img = blockIdx.x / 200;        // img = ci*8 + bi
  int blk = blockIdx.x % 200;
  int ci = img >> 3, bi = img & 7;
  const float* ob = outputs + (size_t)(bi*NCH + ci*6)*HW;
  const float* lb = labels  + (size_t)(bi*NCH + ci*6)*HW;
  const float* mp = tmask   + (size_t)bi*HW;
  unsigned char* mw = maskb + (size_t)img*HW;

  float ka0=0,ka1=0,ka2=0,ka3=0,ka4=0;
  float kb0=0,kb1=0,kb2=0,kb3=0,kb4=0;
  float kc0=0,kc1=0,kc2=0,kc3=0,kc4=0;
  float af=0,bf=0,cf=0;          // text fast
  float ab_=0,bb_=0,cb_=0;       // text fallback
  unsigned pos=0, neg=0;

  #pragma unroll
  for (int it=0; it<2; it++){
    int px = blk*2048 + it*1024 + (int)threadIdx.x*4;
    float4 ov0 = *(const float4*)(ob + 0*HW + px);
    float4 ov1 = *(const float4*)(ob + 1*HW + px);
    float4 ov2 = *(const float4*)(ob + 2*HW + px);
    float4 ov3 = *(const float4*)(ob + 3*HW + px);
    float4 ov4 = *(const float4*)(ob + 4*HW + px);
    float4 ov5 = *(const float4*)(ob + 5*HW + px);
    float4 lv0 = *(const float4*)(lb + 0*HW + px);
    float4 lv1 = *(const float4*)(lb + 1*HW + px);
    float4 lv2 = *(const float4*)(lb + 2*HW + px);
    float4 lv3 = *(const float4*)(lb + 3*HW + px);
    float4 lv4 = *(const float4*)(lb + 4*HW + px);
    float4 lv5 = *(const float4*)(lb + 5*HW + px);
    float4 mv  = *(const float4*)(mp + px);

    float oo[6][4] = {{ov0.x,ov0.y,ov0.z,ov0.w},{ov1.x,ov1.y,ov1.z,ov1.w},
                      {ov2.x,ov2.y,ov2.z,ov2.w},{ov3.x,ov3.y,ov3.z,ov3.w},
                      {ov4.x,ov4.y,ov4.z,ov4.w},{ov5.x,ov5.y,ov5.z,ov5.w}};
    float ll[6][4] = {{lv0.x,lv0.y,lv0.z,lv0.w},{lv1.x,lv1.y,lv1.z,lv1.w},
                      {lv2.x,lv2.y,lv2.z,lv2.w},{lv3.x,lv3.y,lv3.z,lv3.w},
                      {lv4.x,lv4.y,lv4.z,lv4.w},{lv5.x,lv5.y,lv5.z,lv5.w}};
    float tmv[4] = {mv.x,mv.y,mv.z,mv.w};
    unsigned char mby[4];

    #pragma unroll
    for (int c=0;c<4;c++){
      float t  = oo[5][c];
      float g  = ll[5][c];
      float tm = tmv[c];
      bool tpos  = (tm > 0.5f);
      bool isneg = (g <= 0.5f);
      bool selk  = (t > 0.0f) && tpos;
      pos += (unsigned)((!isneg) && tpos);
      neg += (unsigned)isneg;
      mby[c] = (unsigned char)((selk?1u:0u)|(tpos?2u:0u)|(isneg?4u:0u));

      float s5 = sigm(t);
      // text fast path: binary mask tm>0.5 (m^2 == m)
      float mf = tpos ? 1.0f : 0.0f;
      af += mf * (s5*g);
      bf += mf * (s5*s5);
      cf += mf * (g*g);
      // text fallback: continuous mask tm
      float pfb = s5*tm, tfb = g*tm;
      ab_ += pfb*tfb; bb_ += pfb*pfb; cb_ += tfb*tfb;
      // kernel channels: binary mask selk
      float mk = selk ? 1.0f : 0.0f;
      {
        float s, l;
        s = sigm(oo[0][c]); l = ll[0][c];
        ka0 += mk*(s*l); kb0 += mk*(s*s); kc0 += mk*(l*l);
        s = sigm(oo[1][c]); l = ll[1][c];
        ka1 += mk*(s*l); kb1 += mk*(s*s); kc1 += mk*(l*l);
        s = sigm(oo[2][c]); l = ll[2][c];
        ka2 += mk*(s*l); kb2 += mk*(s*s); kc2 += mk*(l*l);
        s = sigm(oo[3][c]); l = ll[3][c];
        ka3 += mk*(s*l); kb3 += mk*(s*s); kc3 += mk*(l*l);
        s = sigm(oo[4][c]); l = ll[4][c];
        ka4 += mk*(s*l); kb4 += mk*(s*s); kc4 += mk*(l*l);
      }
    }
    *(uchar4*)(mw + px) = make_uchar4(mby[0],mby[1],mby[2],mby[3]);
  }

  // wave reduce 23 values (counts as exact f32 ints)
  float red[23] = {af,bf,cf, ab_,bb_,cb_,
                   ka0,kb0,kc0, ka1,kb1,kc1, ka2,kb2,kc2,
                   ka3,kb3,kc3, ka4,kb4,kc4,
                   (float)pos, (float)neg};
  #pragma unroll
  for (int k=0;k<23;k++){
    #pragma unroll
    for (int o=32;o;o>>=1) red[k] += __shfl_down(red[k],o,64);
  }
  __shared__ float sred[4][23];
  int wv = threadIdx.x >> 6, ln = threadIdx.x & 63;
  if (ln==0){
    #pragma unroll
    for (int k=0;k<23;k++) sred[wv][k] = red[k];
  }
  __syncthreads();
  int t = threadIdx.x;
  if (t < 23){
    float v = sred[0][t]+sred[1][t]+sred[2][t]+sred[3][t];
    float* dst;
    if      (t < 3)  dst = tfastA + img*3 + t;
    else if (t < 6)  dst = tfbA   + img*3 + (t-3);
    else if (t < 21) dst = kaccA  + img*15 + (t-6);
    else if (t ==21) dst = posF + img;
    else             dst = negF + img;
    atomicAdd(dst, v);
  }
}

// K2: decide per image. fast/fallback -> select precomputed sums into tacc, done.
// generic (0 < negnum < negtotal) -> radix path fills thrA, k_dtext fills tacc.
__global__ void k_decide(
    const float* __restrict__ posF, const float* __restrict__ negF,
    const float* __restrict__ tfastA, const float* __restrict__ tfbA,
    float* __restrict__ tacc, unsigned* __restrict__ doneA,
    unsigned* __restrict__ negnumA, float* __restrict__ thrA)
{
  int img = threadIdx.x;
  if (img >= 16) return;
  float pos = posF[img], negt = negF[img];      // exact integers in f32
  float nn = fminf(pos*3.0f, negt);
  bool fb   = (pos == 0.0f) || (nn == 0.0f);
  bool fast = (!fb) && (nn == negt);
  thrA[img] = 0.0f;
  if (fb || fast){
    doneA[img] = 1u; negnumA[img] = 1u;
    const float* src = fb ? (tfbA + img*3) : (tfastA + img*3);
    tacc[img*3+0] = src[0];
    tacc[img*3+1] = src[1];
    tacc[img*3+2] = src[2];
  } else {
    doneA[img] = 0u;
    negnumA[img] = (unsigned)(nn + 0.5f);
  }
}

// ---- generic radix path (early-exits when doneA[img]) ----

__global__ __launch_bounds__(256) void k_hista(
    const float* __restrict__ outputs, const unsigned char* __restrict__ maskb,
    const unsigned* __restrict__ doneA, unsigned* __restrict__ histA)
{
  int img = blockIdx.x / 50;
  if (doneA[img]) return;
  int blk = blockIdx.x % 50;
  int ci = img>>3, bi = img&7;
  const float* tp = outputs + (size_t)(bi*NCH + ci*6 + 5)*HW;
  const unsigned char* mk = maskb + (size_t)img*HW;
  __shared__ unsigned lh[2048];
  for (int j=threadIdx.x; j<2048; j+=256) lh[j]=0u;
  __syncthreads();
  #pragma unroll
  for (int it=0; it<8; it++){
    int px = blk*8192 + it*1024 + (int)threadIdx.x*4;
    float4 tv = *(const float4*)(tp+px);
    uchar4 mq = *(const uchar4*)(mk+px);
    float tt[4]={tv.x,tv.y,tv.z,tv.w};
    unsigned char ma[4]={mq.x,mq.y,mq.z,mq.w};
    #pragma unroll
    for (int c=0;c<4;c++)
      if (ma[c] & 4) atomicAdd(&lh[flipkey(tt[c]) >> 21], 1u);
  }
  __syncthreads();
  unsigned* gh = histA + (size_t)img*2048u;
  for (int j=threadIdx.x; j<2048; j+=256){
    unsigned v = lh[j];
    if (v) atomicAdd(&gh[j], v);
  }
}

template<int NB>
__device__ void scan_desc(const unsigned* h, unsigned k, unsigned* selOut, unsigned* kremOut)
{
  const int PER = NB/256;
  int t = threadIdx.x;
  unsigned s=0;
  #pragma unroll
  for (int j=0;j<PER;j++) s += h[t*PER+j];
  __shared__ unsigned cs[256];
  cs[t]=s; __syncthreads();
  if (t==0){
    unsigned cum=0, ch=0, kin=k;
    for (int c=255;c>=0;c--){
      if (cum + cs[c] >= k){ ch=(unsigned)c; kin=k-cum; break; }
      cum += cs[c];
    }
    unsigned cum2=0, sel=ch*PER, kr=1;
    for (int x=PER-1;x>=0;x--){
      unsigned v = h[ch*PER+x];
      cum2 += v;
      if (cum2 >= kin){ sel=ch*PER+(unsigned)x; kr = kin - (cum2 - v); break; }
    }
    *selOut = sel; *kremOut = kr;
  }
}

__global__ __launch_bounds__(256) void k_scan_a(
    const unsigned* __restrict__ histA, const unsigned* __restrict__ doneA,
    const unsigned* __restrict__ negnumA, unsigned* __restrict__ sel1A,
    unsigned* __restrict__ krem1A)
{
  int img = blockIdx.x;
  if (doneA[img]) return;
  scan_desc<2048>(histA + (size_t)img*2048u, negnumA[img], &sel1A[img], &krem1A[img]);
}

__global__ __launch_bounds__(256) void k_histb(
    const float* __restrict__ outputs, const unsigned char* __restrict__ maskb,
    const unsigned* __restrict__ sel1A, const unsigned* __restrict__ doneA,
    unsigned* __restrict__ histB)
{
  int img = blockIdx.x / 50;
  if (doneA[img]) return;
  int blk = blockIdx.x % 50;
  int ci = img>>3, bi = img&7;
  unsigned sel1 = sel1A[img];
  const float* tp = outputs + (size_t)(bi*NCH + ci*6 + 5)*HW;
  const unsigned char* mk = maskb + (size_t)img*HW;
  __shared__ unsigned lh[2048];
  for (int j=threadIdx.x; j<2048; j+=256) lh[j]=0u;
  __syncthreads();
  #pragma unroll
  for (int it=0; it<8; it++){
    int px = blk*8192 + it*1024 + (int)threadIdx.x*4;
    float4 tv = *(const float4*)(tp+px);
    uchar4 mq = *(const uchar4*)(mk+px);
    float tt[4]={tv.x,tv.y,tv.z,tv.w};
    unsigned char ma[4]={mq.x,mq.y,mq.z,mq.w};
    #pragma unroll
    for (int c=0;c<4;c++){
      if (ma[c] & 4){
        unsigned key = flipkey(tt[c]);
        if ((key>>21) == sel1) atomicAdd(&lh[(key>>10) & 0x7FFu], 1u);
      }
    }
  }
  __syncthreads();
  unsigned* gh = histB + (size_t)img*2048u;
  for (int j=threadIdx.x; j<2048; j+=256){
    unsigned v = lh[j];
    if (v) atomicAdd(&gh[j], v);
  }
}

__global__ __launch_bounds__(256) void k_scan_b(
    const unsigned* __restrict__ histB, const unsigned* __restrict__ krem1A,
    const unsigned* __restrict__ doneA, unsigned* __restrict__ sel2A,
    unsigned* __restrict__ krem2A)
{
  int img = blockIdx.x;
  if (doneA[img]) return;
  scan_desc<2048>(histB + (size_t)img*2048u, krem1A[img], &sel2A[img], &krem2A[img]);
}

__global__ __launch_bounds__(256) void k_histc(
    const float* __restrict__ outputs, const unsigned char* __restrict__ maskb,
    const unsigned* __restrict__ sel1A, const unsigned* __restrict__ sel2A,
    const unsigned* __restrict__ doneA, unsigned* __restrict__ histC)
{
  int img = blockIdx.x / 50;
  if (doneA[img]) return;
  int blk = blockIdx.x % 50;
  int ci = img>>3, bi = img&7;
  unsigned p22 = (sel1A[img]<<11) | sel2A[img];
  const float* tp = outputs + (size_t)(bi*NCH + ci*6 + 5)*HW;
  const unsigned char* mk = maskb + (size_t)img*HW;
  __shared__ unsigned lh[1024];
  for (int j=threadIdx.x; j<1024; j+=256) lh[j]=0u;
  __syncthreads();
  #pragma unroll
  for (int it=0; it<8; it++){
    int px = blk*8192 + it*1024 + (int)threadIdx.x*4;
    float4 tv = *(const float4*)(tp+px);
    uchar4 mq = *(const uchar4*)(mk+px);
    float tt[4]={tv.x,tv.y,tv.z,tv.w};
    unsigned char ma[4]={mq.x,mq.y,mq.z,mq.w};
    #pragma unroll
    for (int c=0;c<4;c++){
      if (ma[c] & 4){
        unsigned key = flipkey(tt[c]);
        if ((key>>10) == p22) atomicAdd(&lh[key & 0x3FFu], 1u);
      }
    }
  }
  __syncthreads();
  unsigned* gh = histC + (size_t)img*1024u;
  for (int j=threadIdx.x; j<1024; j+=256){
    unsigned v = lh[j];
    if (v) atomicAdd(&gh[j], v);
  }
}

__global__ __launch_bounds__(256) void k_scan_c(
    const unsigned* __restrict__ histC, const unsigned* __restrict__ sel1A,
    const unsigned* __restrict__ sel2A, const unsigned* __restrict__ krem2A,
    const unsigned* __restrict__ doneA, float* __restrict__ thrA)
{
  int img = blockIdx.x;
  if (doneA[img]) return;
  __shared__ unsigned sel3, kr;
  scan_desc<1024>(histC + (size_t)img*1024u, krem2A[img], &sel3, &kr);
  __syncthreads();
  if (threadIdx.x==0){
    unsigned key = (sel1A[img]<<21) | (sel2A[img]<<10) | sel3;
    thrA[img] = unflip(key);
  }
}

// generic-path text dice (only runs when doneA[img]==0; dormant for this data)
__global__ __launch_bounds__(256) void k_dtext(
    const float* __restrict__ outputs, const float* __restrict__ labels,
    const unsigned char* __restrict__ maskb, const unsigned* __restrict__ doneA,
    const float* __restrict__ thrA, float* __restrict__ tacc)
{
  int img = blockIdx.x / 50;
  if (doneA[img]) return;
  int blk = blockIdx.x % 50;
  int ci = img>>3, bi = img&7;
  const float* tp = outputs + (size_t)(bi*NCH + ci*6 + 5)*HW;
  const float* gp = labels  + (size_t)(bi*NCH + ci*6 + 5)*HW;
  const unsigned char* mk = maskb + (size_t)img*HW;
  float thr = thrA[img];
  float sa=0.f, sb=0.f, sc=0.f;
  #pragma unroll
  for (int half=0; half<2; half++){
    int base = blk*8192 + half*4096 + (int)threadIdx.x*4;
    float4 pv0 = *(const float4*)(tp+base);
    float4 pv1 = *(const float4*)(tp+base+1024);
    float4 pv2 = *(const float4*)(tp+base+2048);
    float4 pv3 = *(const float4*)(tp+base+3072);
    float4 gv0 = *(const float4*)(gp+base);
    float4 gv1 = *(const float4*)(gp+base+1024);
    float4 gv2 = *(const float4*)(gp+base+2048);
    float4 gv3 = *(const float4*)(gp+base+3072);
    uchar4 mq0 = *(const uchar4*)(mk+base);
    uchar4 mq1 = *(const uchar4*)(mk+base+1024);
    uchar4 mq2 = *(const uchar4*)(mk+base+2048);
    uchar4 mq3 = *(const uchar4*)(mk+base+3072);
    float pa[16]={pv0.x,pv0.y,pv0.z,pv0.w, pv1.x,pv1.y,pv1.z,pv1.w,
                  pv2.x,pv2.y,pv2.z,pv2.w, pv3.x,pv3.y,pv3.z,pv3.w};
    float ga[16]={gv0.x,gv0.y,gv0.z,gv0.w, gv1.x,gv1.y,gv1.z,gv1.w,
                  gv2.x,gv2.y,gv2.z,gv2.w, gv3.x,gv3.y,gv3.z,gv3.w};
    unsigned char ma[16]={mq0.x,mq0.y,mq0.z,mq0.w, mq1.x,mq1.y,mq1.z,mq1.w,
                          mq2.x,mq2.y,mq2.z,mq2.w, mq3.x,mq3.y,mq3.z,mq3.w};
    #pragma unroll
    for (int c=0;c<16;c++){
      float m = (((pa[c] >= thr) || (ga[c] > 0.5f)) && (ma[c] & 2)) ? 1.0f : 0.0f;
      float p = sigm(pa[c]) * m;
      float tt = ga[c]*m;
      sa += p*tt; sb += p*p; sc += tt*tt;
    }
  }
  #pragma unroll
  for (int o=32;o;o>>=1){
    sa += __shfl_down(sa,o,64); sb += __shfl_down(sb,o,64); sc += __shfl_down(sc,o,64);
  }
  __shared__ float ra[4], rb[4], rc[4];
  int wv = threadIdx.x>>6, ln = threadIdx.x&63;
  if (ln==0){ ra[wv]=sa; rb[wv]=sb; rc[wv]=sc; }
  __syncthreads();
  if (threadIdx.x==0){
    float* acc = tacc + img*3;
    atomicAdd(acc+0, ra[0]+ra[1]+ra[2]+ra[3]);
    atomicAdd(acc+1, rb[0]+rb[1]+rb[2]+rb[3]);
    atomicAdd(acc+2, rc[0]+rc[1]+rc[2]+rc[3]);
  }
}

// K10: finalize 3 outputs
__global__ void k_final(const float* __restrict__ tacc, const float* __restrict__ kacc,
                        float* __restrict__ out)
{
  if (blockIdx.x==0 && threadIdx.x==0){
    const float EPSF = 1e-4f;
    float ltA[2], lkA[2];
    for (int i=0;i<2;i++){
      float lt=0.f;
      for (int b=0;b<8;b++){
        int img=i*8+b;
        float a=tacc[img*3], p2=tacc[img*3+1]+EPSF, t2=tacc[img*3+2]+EPSF;
        lt += 1.f - 2.f*a/(p2+t2);
      }
      lt *= 0.125f;
      float lk=0.f;
      for (int b=0;b<8;b++) for (int k=0;k<5;k++){
        int idx=((i*8+b)*5+k)*3;
        float a=kacc[idx], p2=kacc[idx+1]+EPSF, t2=kacc[idx+2]+EPSF;
        lk += 1.f - 2.f*a/(p2+t2);
      }
      lk /= 40.f;
      ltA[i]=lt; lkA[i]=lk;
    }
    float l0 = 0.7f*ltA[0] + 0.3f*lkA[0];
    float l1 = 0.7f*ltA[1] + 0.3f*lkA[1];
    out[0]=0.5f*(l0+l1);
    out[1]=0.5f*(ltA[0]+ltA[1]);
    out[2]=0.5f*(lkA[0]+lkA[1]);
  }
}

extern "C" void kernel_launch(void* const* d_in, const int* in_sizes, int n_in,
                              void* d_out, int out_size, void* d_ws, size_t ws_size,
                              hipStream_t stream)
{
  const float* outputs = (const float*)d_in[0];
  const float* labels  = (const float*)d_in[1];
  const float* tmask   = (const float*)d_in[2];
  float* out = (float*)d_out;
  char* ws = (char*)d_ws;
  float* tacc      = (float*)(ws + OFF_TACC);
  float* kacc      = (float*)(ws + OFF_KACC);
  float* tfastA    = (float*)(ws + OFF_TFAST);
  float* tfbA      = (float*)(ws + OFF_TFB);
  float* posF      = (float*)(ws + OFF_POSF);
  float* negF      = (float*)(ws + OFF_NEGF);
  unsigned* doneA  = (unsigned*)(ws + OFF_DONE);
  unsigned* negnumA= (unsigned*)(ws + OFF_NEGNUM);
  unsigned* sel1A  = (unsigned*)(ws + OFF_SEL1);
  unsigned* krem1A = (unsigned*)(ws + OFF_KREM1);
  unsigned* sel2A  = (unsigned*)(ws + OFF_SEL2);
  unsigned* krem2A = (unsigned*)(ws + OFF_KREM2);
  float* thrA      = (float*)(ws + OFF_THR);
  unsigned* histA  = (unsigned*)(ws + OFF_HA);
  unsigned* histB  = (unsigned*)(ws + OFF_HB);
  unsigned* histC  = (unsigned*)(ws + OFF_HC);
  unsigned char* maskb = (unsigned char*)(ws + OFF_MASK);

  hipMemsetAsync(ws, 0, OFF_META_END, stream);   // accs + meta + hists (~324 KiB)
  k_main  <<<3200,256,0,stream>>>(outputs, labels, tmask, maskb, posF, negF,
                                  tfastA, tfbA, kacc);
  k_decide<<<1,64,0,stream>>>(posF, negF, tfastA, tfbA, tacc, doneA, negnumA, thrA);
  k_hista <<<800,256,0,stream>>>(outputs, maskb, doneA, histA);
  k_scan_a<<<16,256,0,stream>>>(histA, doneA, negnumA, sel1A, krem1A);
  k_histb <<<800,256,0,stream>>>(outputs, maskb, sel1A, doneA, histB);
  k_scan_b<<<16,256,0,stream>>>(histB, krem1A, doneA, sel2A, krem2A);
  k_histc <<<800,256,0,stream>>>(outputs, maskb, sel1A, sel2A, doneA, histC);
  k_scan_c<<<16,256,0,stream>>>(histC, sel1A, sel2A, krem2A, doneA, thrA);
  k_dtext <<<800,256,0,stream>>>(outputs, labels, maskb, doneA, thrA, tacc);
  k_final <<<1,64,0,stream>>>(tacc, kacc, out);
}